// Round 16
// baseline (175.707 us; speedup 1.0000x reference)
//
#include <hip/hip_runtime.h>
#include <hip/hip_fp16.h>

typedef _Float16 f16x8 __attribute__((ext_vector_type(8)));
typedef float f32x16 __attribute__((ext_vector_type(16)));

// LeNet C3 connection table: input channel ii feeds CONN[ii][j] with weight[j][ii].
__device__ constexpr int CONN[6][10] = {
    {0, 4, 5, 6, 9, 10, 11, 12, 14, 15},
    {0, 1, 5, 6, 7, 10, 11, 12, 13, 15},
    {0, 1, 2, 6, 7, 8, 11, 13, 14, 15},
    {1, 2, 3, 6, 7, 8, 9, 12, 14, 15},
    {2, 3, 4, 7, 8, 9, 10, 12, 13, 15},
    {3, 4, 5, 8, 9, 10, 11, 13, 14, 15}};

__device__ constexpr int CNT[16] = {3,3,3,3,3,3,4,4,4,4,4,4,4,4,4,6};

__device__ __forceinline__ f16x8 u4_to_h8(uint4 u) { f16x8 r; __builtin_memcpy(&r, &u, 16); return r; }

#define PITCH_DW 128            // pow2 pitch, no halo (wrap feeds only zero-weight/masked slots)
#define PLANE_DW 3200           // 25 rows x 128
#define SIN_DW   19200          // 6 planes
#define LDS_DW   (19200 + 3840) // + 7680-half weight panel = 92160 B

// Block: 256x x 21y tile, 8 waves x one 32-x strip each -> full output page per
// y-phase. 1 block/CU (90KB LDS) halves concurrent plane-streams/CU to 16.
// Grid 768 = exactly 3 generations. Weight panel built in-LDS (no prep dispatch).
__global__ __launch_bounds__(512, 2) void c3_mfma(
    const float* __restrict__ x, const float* __restrict__ w,
    const float* __restrict__ bias, float* __restrict__ out)
{
    extern __shared__ unsigned s_lds[];
    unsigned short* s_panel = reinterpret_cast<unsigned short*>(s_lds + SIN_DW);

    const int tid = threadIdx.x;
    // 768 blocks = 64 n x 12 y-tiles; XCD chunks of 96 (bijective).
    const int id = (blockIdx.x & 7) * 96 + (blockIdx.x >> 3);
    const int by = id % 12;
    const int n  = id / 12;
    const int Y0 = by * 21;                 // max 231; stage rows to 255, store to 251: exact
    const float* xin = x + (size_t)n * 6 * 65536;

    // ---- build weight A-panel in LDS (mfma_f32_32x32x16_f16, M=32, 15 MFMAs):
    // slice = ms + 15*kb; ii = slice/5; r = slice%5;
    // panel[(ms*64+lane)*8+j] = (ch<16 && j<5) ? w_full[ch][ii][r][j] : 0
    for (int t = tid; t < 7680; t += 512) {
        int j = t & 7, lane = (t >> 3) & 63, ms = t >> 9;
        int ch = lane & 31, kb = lane >> 5;
        int slice = ms + 15 * kb;
        int ii = slice / 5, r = slice % 5;
        float val = 0.f;
        if (ch < 16 && j < 5)
            for (int jj = 0; jj < 10; ++jj)
                if (CONN[ii][jj] == ch) val = w[jj * 150 + ii * 25 + r * 5 + j];
        __half h = __float2half(val);
        unsigned short u; __builtin_memcpy(&u, &h, 2);
        s_panel[t] = u;
    }

    // ---- stage 6ch x 25row x 256col f32 -> fp16 (pitch 128 dw, no guards) ----
    for (int i = tid; i < 9600; i += 512) {
        int c4  = i & 63;
        int t   = i >> 6;                  // 0..149
        int ch  = t / 25;
        int row = t - ch * 25;
        float4 v = *reinterpret_cast<const float4*>(
            xin + (size_t)ch * 65536 + (size_t)(Y0 + row) * 256 + c4 * 4);
        __half2 lo = __floats2half2_rn(v.x, v.y);
        __half2 hi = __floats2half2_rn(v.z, v.w);
        uint2 u; __builtin_memcpy(&u.x, &lo, 4); __builtin_memcpy(&u.y, &hi, 4);
        *reinterpret_cast<uint2*>(&s_lds[ch * PLANE_DW + row * PITCH_DW + c4 * 2]) = u;
    }
    __syncthreads();

    const int lane = tid & 63;
    const int wv   = tid >> 6;     // 8 waves: strip x = [32wv, 32wv+31]
    const int nn   = lane & 31;    // B-col = x; C-col = x
    const int kb   = lane >> 5;    // k-block; C rows += 4*kb; window planes 3kb..3kb+2

    // ---- weight A-frags from LDS panel ----
    f16x8 W[15];
    {
        const uint4* p4 = reinterpret_cast<const uint4*>(s_panel);
        #pragma unroll
        for (int ms = 0; ms < 15; ++ms) W[ms] = u4_to_h8(p4[ms * 64 + lane]);
    }

    // ---- C init: regs 0..7 = bias for ch=(reg&3)+8*(reg>>2)+4*kb; 8..15 = 0 ----
    f32x16 cinit;
    #pragma unroll
    for (int reg = 0; reg < 8; ++reg) {
        int ch = (reg & 3) + 8 * (reg >> 2) + 4 * kb;
        cinit[reg] = bias[ch] * (float)CNT[ch];
    }
    #pragma unroll
    for (int reg = 8; reg < 16; ++reg) cinit[reg] = 0.f;

    const int gx  = 32 * wv + nn;
    const bool ok = gx < 252;
    const int pb  = 3 * kb * PLANE_DW + (gx >> 1);
    const bool odd = (gx >> 1) & 1;
    const unsigned shb = (unsigned)((nn & 1) * 16);

    auto loadf = [&](int dw) -> f16x8 {
        int d0 = dw & ~1;
        uint2 r0 = *reinterpret_cast<const uint2*>(&s_lds[d0]);
        uint2 r1 = *reinterpret_cast<const uint2*>(&s_lds[d0 + 2]);
        uint2 r2 = *reinterpret_cast<const uint2*>(&s_lds[d0 + 4]);
        unsigned e0 = odd ? r0.y : r0.x;
        unsigned e1 = odd ? r1.x : r0.y;
        unsigned e2 = odd ? r1.y : r1.x;
        unsigned e3 = odd ? r2.x : r1.y;
        unsigned e4 = odd ? r2.y : r2.x;
        unsigned o0 = (unsigned)((((unsigned long long)e1 << 32) | e0) >> shb);
        unsigned o1 = (unsigned)((((unsigned long long)e2 << 32) | e1) >> shb);
        unsigned o2 = (unsigned)((((unsigned long long)e3 << 32) | e2) >> shb);
        unsigned o3 = (unsigned)((((unsigned long long)e4 << 32) | e3) >> shb);
        return u4_to_h8(make_uint4(o0, o1, o2, o3));
    };

    // prologue: rows 0..4 x 3 planes
    f16x8 F00 = loadf(pb + 0*PITCH_DW), F01 = loadf(pb + 1*PITCH_DW),
          F02 = loadf(pb + 2*PITCH_DW), F03 = loadf(pb + 3*PITCH_DW),
          F04 = loadf(pb + 4*PITCH_DW);
    f16x8 F10 = loadf(pb + PLANE_DW + 0*PITCH_DW), F11 = loadf(pb + PLANE_DW + 1*PITCH_DW),
          F12 = loadf(pb + PLANE_DW + 2*PITCH_DW), F13 = loadf(pb + PLANE_DW + 3*PITCH_DW),
          F14 = loadf(pb + PLANE_DW + 4*PITCH_DW);
    f16x8 F20 = loadf(pb + 2*PLANE_DW + 0*PITCH_DW), F21 = loadf(pb + 2*PLANE_DW + 1*PITCH_DW),
          F22 = loadf(pb + 2*PLANE_DW + 2*PITCH_DW), F23 = loadf(pb + 2*PLANE_DW + 3*PITCH_DW),
          F24 = loadf(pb + 2*PLANE_DW + 4*PITCH_DW);
    int rowOff = 5 * PITCH_DW;

    float* const opg = out + (size_t)n * 16 * 63504 + (size_t)(4 * kb) * 63504 + gx;
    int yoff = Y0 * 252;

#define MFMA32(a, b, c) __builtin_amdgcn_mfma_f32_32x32x16_f16(a, b, c, 0, 0, 0)

#define PHASE(f00,f01,f02,f03,f04, f10,f11,f12,f13,f14, f20,f21,f22,f23,f24)   \
    {                                                                          \
        f32x16 acc = cinit;                                                    \
        acc = MFMA32(W[0],  f00, acc);  acc = MFMA32(W[1],  f01, acc);         \
        acc = MFMA32(W[2],  f02, acc);  acc = MFMA32(W[3],  f03, acc);         \
        acc = MFMA32(W[4],  f04, acc);                                         \
        acc = MFMA32(W[5],  f10, acc);  acc = MFMA32(W[6],  f11, acc);         \
        acc = MFMA32(W[7],  f12, acc);  acc = MFMA32(W[8],  f13, acc);         \
        acc = MFMA32(W[9],  f14, acc);                                         \
        acc = MFMA32(W[10], f20, acc);  acc = MFMA32(W[11], f21, acc);         \
        acc = MFMA32(W[12], f22, acc);  acc = MFMA32(W[13], f23, acc);         \
        acc = MFMA32(W[14], f24, acc);                                         \
        if (ok) {                                                              \
            opg[yoff +  0 * 63504] = acc[0];                                   \
            opg[yoff +  1 * 63504] = acc[1];                                   \
            opg[yoff +  2 * 63504] = acc[2];                                   \
            opg[yoff +  3 * 63504] = acc[3];                                   \
            opg[yoff +  8 * 63504] = acc[4];                                   \
            opg[yoff +  9 * 63504] = acc[5];                                   \
            opg[yoff + 10 * 63504] = acc[6];                                   \
            opg[yoff + 11 * 63504] = acc[7];                                   \
        }                                                                      \
        f00 = loadf(pb + rowOff);                                              \
        f10 = loadf(pb + PLANE_DW + rowOff);                                   \
        f20 = loadf(pb + 2 * PLANE_DW + rowOff);                               \
        rowOff += PITCH_DW; yoff += 252;                                       \
    }
    // note: last phase's reload reads into the panel region (in-bounds, unused)

#define P0 PHASE(F00,F01,F02,F03,F04, F10,F11,F12,F13,F14, F20,F21,F22,F23,F24)
#define P1 PHASE(F01,F02,F03,F04,F00, F11,F12,F13,F14,F10, F21,F22,F23,F24,F20)
#define P2 PHASE(F02,F03,F04,F00,F01, F12,F13,F14,F10,F11, F22,F23,F24,F20,F21)
#define P3 PHASE(F03,F04,F00,F01,F02, F13,F14,F10,F11,F12, F23,F24,F20,F21,F22)
#define P4 PHASE(F04,F00,F01,F02,F03, F14,F10,F11,F12,F13, F24,F20,F21,F22,F23)

    P0 P1 P2 P3 P4
    P0 P1 P2 P3 P4
    P0 P1 P2 P3 P4
    P0 P1 P2 P3 P4
    P0
#undef P0
#undef P1
#undef P2
#undef P3
#undef P4
#undef PHASE
#undef MFMA32
}

extern "C" void kernel_launch(void* const* d_in, const int* in_sizes, int n_in,
                              void* d_out, int out_size, void* d_ws, size_t ws_size,
                              hipStream_t stream) {
    const float* x    = (const float*)d_in[0];  // (64,6,256,256)
    const float* w    = (const float*)d_in[1];  // (10,6,5,5)
    const float* bias = (const float*)d_in[2];  // (1,16,1,1)
    float* out = (float*)d_out;                 // (64,16,252,252)

    static_assert(LDS_DW * 4 == 92160, "LDS size");
    hipFuncSetAttribute(reinterpret_cast<const void*>(c3_mfma),
                        hipFuncAttributeMaxDynamicSharedMemorySize, LDS_DW * 4);
    hipLaunchKernelGGL(c3_mfma, dim3(768), dim3(512), LDS_DW * 4, stream,
                       x, w, bias, out);
}